// Round 4
// baseline (180.481 us; speedup 1.0000x reference)
//
#include <hip/hip_runtime.h>
#include <cstdint>

#define B_    32
#define T_    2048
#define D_    80
#define T2_   511
#define NROW  16352      // B_*T2_
#define GK    720        // INPUT_DIM
#define CBD   512
#define CBS   1024
#define HMASK 8176       // 16352/2
#define HN    2621440    // B_*T_*D_/2
#define NP    16384      // padded rows
#define KB    23         // 736/32 k-blocks (k=720 is the norm-augment slot)

using bfrag = __attribute__((ext_vector_type(8))) short;   // 8 bf16 = 4 VGPR
using f32x4 = __attribute__((ext_vector_type(4))) float;
using s4    = __attribute__((ext_vector_type(4))) short;

__device__ inline ushort f2bf(float f){                    // RNE f32->bf16
  uint32_t u = __float_as_uint(f);
  uint32_t r = (u + 0x7FFFu + ((u >> 16) & 1u)) >> 16;
  return (ushort)r;
}
__device__ inline float bf2f(ushort h){ return __uint_as_float(((uint32_t)h) << 16); }

#define GLL16(gsrc, ldst) __builtin_amdgcn_global_load_lds( \
    (__attribute__((address_space(1))) void*)(gsrc), \
    (__attribute__((address_space(3))) void*)(ldst), 16, 0, 0)

// ---------------- threefry2x32 (exact JAX schedule) ----------------
__host__ __device__ inline uint32_t rotl_(uint32_t v, int d){ return (v<<d)|(v>>(32-d)); }

__host__ __device__ inline void tf2x32(uint32_t k0, uint32_t k1, uint32_t& x0, uint32_t& x1){
  uint32_t ks2 = k0 ^ k1 ^ 0x1BD11BDAu;
  x0 += k0; x1 += k1;
  const int r0[4] = {13,15,26,6}, r1[4] = {17,29,16,24};
#pragma unroll
  for (int i=0;i<4;i++){ x0 += x1; x1 = rotl_(x1, r0[i]); x1 ^= x0; }
  x0 += k1; x1 += ks2 + 1u;
#pragma unroll
  for (int i=0;i<4;i++){ x0 += x1; x1 = rotl_(x1, r1[i]); x1 ^= x0; }
  x0 += ks2; x1 += k0 + 2u;
#pragma unroll
  for (int i=0;i<4;i++){ x0 += x1; x1 = rotl_(x1, r0[i]); x1 ^= x0; }
  x0 += k0; x1 += k1 + 3u;
#pragma unroll
  for (int i=0;i<4;i++){ x0 += x1; x1 = rotl_(x1, r1[i]); x1 ^= x0; }
  x0 += k1; x1 += ks2 + 4u;
#pragma unroll
  for (int i=0;i<4;i++){ x0 += x1; x1 = rotl_(x1, r0[i]); x1 ^= x0; }
  x0 += ks2; x1 += k0 + 5u;
}

// XLA ErfInv32 (Giles) — matches lax.erf_inv f32
__device__ inline float erfinv_f(float x){
  float w = -log1pf(-x*x);
  float p;
  if (w < 5.0f){
    w -= 2.5f;
    p = 2.81022636e-08f;
    p = fmaf(p, w, 3.43273939e-07f);
    p = fmaf(p, w, -3.5233877e-06f);
    p = fmaf(p, w, -4.39150654e-06f);
    p = fmaf(p, w, 0.00021858087f);
    p = fmaf(p, w, -0.00125372503f);
    p = fmaf(p, w, -0.00417768164f);
    p = fmaf(p, w, 0.246640727f);
    p = fmaf(p, w, 1.50140941f);
  } else {
    w = sqrtf(w) - 3.0f;
    p = -0.000200214257f;
    p = fmaf(p, w, 0.000100950558f);
    p = fmaf(p, w, 0.00134934322f);
    p = fmaf(p, w, -0.00367342844f);
    p = fmaf(p, w, 0.00573950773f);
    p = fmaf(p, w, -0.0076224613f);
    p = fmaf(p, w, 0.00943887047f);
    p = fmaf(p, w, 1.00167406f);
    p = fmaf(p, w, 2.83297682f);
  }
  return p * x;
}

__device__ inline int label_len(int L){ return (((L - 3) / 2) - 2) / 2 + 1; }

// ---------------- kernel 1: codebook norms -> augment row (k=720) of W panels ----------------
__global__ void cbnorm_k(const float* __restrict__ cb, ushort* __restrict__ W0, ushort* __restrict__ W1){
  int c = blockIdx.x, lane = threadIdx.x;
  double s = 0.0;
  for (int k = lane; k < CBD; k += 64){ float v = cb[c*CBD + k]; s += (double)v * (double)v; }
#pragma unroll
  for (int off = 32; off; off >>= 1) s += __shfl_down(s, off);
  float nf = (float)s;
  nf = __shfl(nf, 0);
  size_t base = ((size_t)(KB-1)*CBS + c)*32;
  if (lane == 16){
    float h = -0.5f * nf;
    ushort h0 = f2bf(h); ushort h1 = f2bf(h - bf2f(h0));
    W0[base+16] = h0; W1[base+16] = h1;
  } else if (lane > 16 && lane < 32){
    W0[base+lane] = 0; W1[base+lane] = 0;
  }
}

// ---------------- kernel 2: gather stacked S -> split bf16 k-panels [kb][n][kk] ----------------
__global__ void gather_k(const float* __restrict__ raw, ushort* __restrict__ S0, ushort* __restrict__ S1){
  int idx4 = blockIdx.x * 256 + threadIdx.x;    // one thread = 4 consecutive kk
  int kk4 = idx4 & 7;
  int n   = (idx4 >> 3) & (NP - 1);
  int kb  = idx4 >> 17;                          // NP*8 = 2^17
  int b = n / T2_, t2 = n - b * T2_;
  s4 o0, o1;
#pragma unroll
  for (int j = 0; j < 4; ++j){
    int k = kb*32 + kk4*4 + j;
    float v = 0.f;
    if (n < NROW){
      if (k < GK){
        int d = k / 9, rem = k - 9*d;
        int k1 = rem / 3, k2 = rem - 3*k1;
        int tm = 4*t2 + 2*k2 + k1;
        v = raw[(b * T_ + tm) * D_ + d];
      } else if (k == GK) v = 1.f;               // norm-augment slot
    }
    ushort h0 = f2bf(v); ushort h1 = f2bf(v - bf2f(h0));
    o0[j] = (short)h0; o1[j] = (short)h1;
  }
  size_t off = ((size_t)kb*NP + n)*32 + kk4*4;
  *(s4*)&S0[off] = o0;
  *(s4*)&S1[off] = o1;
}

// ---------------- kernel 3: W = P(720x512)*cb^T -> split bf16 k-panels [kb][c][kk] ----------------
__global__ __launch_bounds__(256) void wgemm_k(const float* __restrict__ P, const float* __restrict__ cb,
                                               ushort* __restrict__ W0, ushort* __restrict__ W1){
  __shared__ float sP[16][68];
  __shared__ float sC[16][68];
  int r0 = blockIdx.y * 64, c0 = blockIdx.x * 64;
  int tid = threadIdx.x, tx = tid & 15, ty = tid >> 4;
  float acc[4][4] = {};
  for (int k0 = 0; k0 < CBD; k0 += 16){
    __syncthreads();
    {
      int r = tid >> 2, kq = tid & 3;
      int rr = r0 + r;
      float4 v = {0.f,0.f,0.f,0.f};
      if (rr < GK) v = *(const float4*)&P[rr * CBD + k0 + kq * 4];
      sP[kq*4+0][r] = v.x; sP[kq*4+1][r] = v.y; sP[kq*4+2][r] = v.z; sP[kq*4+3][r] = v.w;
      float4 w = *(const float4*)&cb[(c0 + r) * CBD + k0 + kq * 4];
      sC[kq*4+0][r] = w.x; sC[kq*4+1][r] = w.y; sC[kq*4+2][r] = w.z; sC[kq*4+3][r] = w.w;
    }
    __syncthreads();
#pragma unroll
    for (int kk = 0; kk < 16; ++kk){
      float4 a = *(const float4*)&sP[kk][ty * 4];
      float4 b = *(const float4*)&sC[kk][tx * 4];
      float av[4] = {a.x,a.y,a.z,a.w}, bv[4] = {b.x,b.y,b.z,b.w};
#pragma unroll
      for (int i = 0; i < 4; ++i)
#pragma unroll
        for (int j = 0; j < 4; ++j) acc[i][j] = fmaf(av[i], bv[j], acc[i][j]);
    }
  }
#pragma unroll
  for (int i = 0; i < 4; ++i){
    int r = r0 + ty * 4 + i;
    if (r < GK){
#pragma unroll
      for (int j = 0; j < 4; ++j){
        int c = c0 + tx * 4 + j;
        float v = acc[i][j];
        ushort h0 = f2bf(v); ushort h1 = f2bf(v - bf2f(h0));
        size_t o = ((size_t)(r >> 5) * CBS + c) * 32 + (r & 31);
        W0[o] = h0; W1[o] = h1;
      }
    }
  }
}

// ---------------- kernel 4: score = S*W via 3-pass bf16 MFMA, fused argmin ----------------
__global__ __launch_bounds__(256) void score_k(const ushort* __restrict__ S0, const ushort* __restrict__ S1,
                                               const ushort* __restrict__ W0, const ushort* __restrict__ W1,
                                               float* __restrict__ pval, int* __restrict__ pidx){
  __shared__ __align__(16) ushort lA[2][128*32];
  __shared__ __align__(16) ushort lB[2][128*32];
  int tid = threadIdx.x;
  int lane = tid & 63, wid = tid >> 6;
  int wm = wid >> 1, wn = wid & 1;        // 2x2 waves -> 64x64 tiles
  int g = lane >> 4, lr = lane & 15;
  int n0 = blockIdx.y * 128, c0 = blockIdx.x * 128;
  f32x4 acc[4][4] = {};
  for (int kb = 0; kb < KB; ++kb){
    const ushort* src; ushort* dst;
    if      (wid == 0){ src = S0 + ((size_t)kb*NP  + n0)*32; dst = &lA[0][0]; }
    else if (wid == 1){ src = S1 + ((size_t)kb*NP  + n0)*32; dst = &lA[1][0]; }
    else if (wid == 2){ src = W0 + ((size_t)kb*CBS + c0)*32; dst = &lB[0][0]; }
    else              { src = W1 + ((size_t)kb*CBS + c0)*32; dst = &lB[1][0]; }
    __syncthreads();
#pragma unroll
    for (int q = 0; q < 8; ++q)
      GLL16(src + q*512 + lane*8, dst + q*512);
    __syncthreads();
    bfrag a[2][4], bfr[2][4];
#pragma unroll
    for (int mt = 0; mt < 4; ++mt){
      int m = wm*64 + mt*16 + lr;
      a[0][mt] = *(const bfrag*)&lA[0][m*32 + g*8];
      a[1][mt] = *(const bfrag*)&lA[1][m*32 + g*8];
    }
#pragma unroll
    for (int nt = 0; nt < 4; ++nt){
      int c = wn*64 + nt*16 + lr;
      bfr[0][nt] = *(const bfrag*)&lB[0][c*32 + g*8];
      bfr[1][nt] = *(const bfrag*)&lB[1][c*32 + g*8];
    }
#pragma unroll
    for (int mt = 0; mt < 4; ++mt)
#pragma unroll
      for (int nt = 0; nt < 4; ++nt){
        acc[mt][nt] = __builtin_amdgcn_mfma_f32_16x16x32_bf16(a[0][mt], bfr[0][nt], acc[mt][nt], 0,0,0);
        acc[mt][nt] = __builtin_amdgcn_mfma_f32_16x16x32_bf16(a[0][mt], bfr[1][nt], acc[mt][nt], 0,0,0);
        acc[mt][nt] = __builtin_amdgcn_mfma_f32_16x16x32_bf16(a[1][mt], bfr[0][nt], acc[mt][nt], 0,0,0);
      }
  }
  // epilogue: dist = -2*acc (norms folded in); per-row argmin, first-index tie-break
  float bv[4][4]; int bi[4][4];
#pragma unroll
  for (int mt = 0; mt < 4; ++mt)
#pragma unroll
    for (int r = 0; r < 4; ++r){
      float best = 3.4e38f; int besti = 0;
#pragma unroll
      for (int nt = 0; nt < 4; ++nt){      // nt ascending == col ascending
        float d = -2.f * acc[mt][nt][r];
        int c = c0 + wn*64 + nt*16 + lr;
        if (d < best){ best = d; besti = c; }
      }
      bv[mt][r] = best; bi[mt][r] = besti;
    }
#pragma unroll
  for (int off = 1; off < 16; off <<= 1){
#pragma unroll
    for (int mt = 0; mt < 4; ++mt)
#pragma unroll
      for (int r = 0; r < 4; ++r){
        float ov = __shfl_xor(bv[mt][r], off);
        int   oi = __shfl_xor(bi[mt][r], off);
        if (ov < bv[mt][r] || (ov == bv[mt][r] && oi < bi[mt][r])){ bv[mt][r] = ov; bi[mt][r] = oi; }
      }
  }
  if (lr == 0){
    int p = blockIdx.x*2 + wn;
#pragma unroll
    for (int mt = 0; mt < 4; ++mt)
#pragma unroll
      for (int r = 0; r < 4; ++r){
        int n = n0 + wm*64 + mt*16 + g*4 + r;
        pval[(size_t)p*NP + n] = bv[mt][r];
        pidx[(size_t)p*NP + n] = bi[mt][r];
      }
  }
}

// ---------------- kernel 5: combine 16 partial argmins -> labels ----------------
__global__ void combine_k(const float* __restrict__ pval, const int* __restrict__ pidx,
                          const int* __restrict__ len, float* __restrict__ lb){
  int n = blockIdx.x * 256 + threadIdx.x;
  if (n >= NROW) return;
  float bv = pval[n]; int bi = pidx[n];
#pragma unroll
  for (int p = 1; p < 16; ++p){
    float v = pval[(size_t)p*NP + n]; int ii = pidx[(size_t)p*NP + n];
    if (v < bv || (v == bv && ii < bi)){ bv = v; bi = ii; }
  }
  int b = n / T2_, t2 = n - b * T2_;
  lb[n] = (t2 < label_len(len[b])) ? (float)(bi + 1) : 0.f;
}

// ---------------- kernel 6: mask (threefry uniform, bit-exact) ----------------
__device__ inline void emit_mask(const int* len, float* md, int i, uint32_t bits){
  float u = __uint_as_float((bits >> 9) | 0x3F800000u) - 1.0f;
  int b = i / T2_, t2 = i - b * T2_;
  bool m = (u < 0.1f) && (t2 < label_len(len[b]));
  md[i] = m ? 1.0f : 0.0f;
}

__global__ void mask_k(const int* __restrict__ len, float* __restrict__ md, uint32_t km0, uint32_t km1){
  int j = blockIdx.x * 256 + threadIdx.x;
  if (j >= HMASK) return;
  uint32_t x0 = (uint32_t)j, x1 = (uint32_t)(j + HMASK);
  tf2x32(km0, km1, x0, x1);
  emit_mask(len, md, j, x0);
  emit_mask(len, md, j + HMASK, x1);
}

// ---------------- kernel 7: masked_feats (threefry normal, bit-exact bits) ----------------
__device__ inline void emit_feat(const float* aug, const float* md, float* mf, int i, uint32_t bits){
  int tabs = i / D_;
  int t = tabs & (T_ - 1);
  int b = i / (D_ * T_);
  int lo = (t < 3) ? 0 : ((t - 3) >> 2);
  int hi = t >> 2; if (hi > T2_ - 1) hi = T2_ - 1;
  bool m = false;
  for (int t2 = lo; t2 <= hi; ++t2) m = m || (md[b * T2_ + t2] != 0.f);
  float v;
  if (m){
    float f = __uint_as_float((bits >> 9) | 0x3F800000u) - 1.0f;
    const float LOV = -0.99999994f;
    float u = fmaf(f, 2.0f, LOV);
    u = fmaxf(LOV, u);
    v = 0.1f * (1.41421356f * erfinv_f(u));
  } else {
    v = aug[i];
  }
  mf[i] = v;
}

__global__ void feats_k(const float* __restrict__ aug, const float* __restrict__ md,
                        float* __restrict__ mf, uint32_t kn0, uint32_t kn1){
  int j = blockIdx.x * 256 + threadIdx.x;
  uint32_t x0 = (uint32_t)j, x1 = (uint32_t)(j + HN);
  tf2x32(kn0, kn1, x0, x1);
  emit_feat(aug, md, mf, j, x0);
  emit_feat(aug, md, mf, j + HN, x1);
}

// ---------------- host ----------------
extern "C" void kernel_launch(void* const* d_in, const int* in_sizes, int n_in,
                              void* d_out, int out_size, void* d_ws, size_t ws_size,
                              hipStream_t stream){
  const float* raw  = (const float*)d_in[0];
  const float* aug  = (const float*)d_in[1];
  const int*   len  = (const int*)  d_in[2];
  const float* proj = (const float*)d_in[3];
  const float* cb   = (const float*)d_in[4];

  float* out = (float*)d_out;
  float* mf  = out;                       // (B,T,D)   5,242,880
  float* lb  = out + 5242880;             // (1,B,T2)     16,352
  float* md  = out + 5259232;             // (B,T2)       16,352

  ushort* w  = (ushort*)d_ws;
  ushort* W0 = w;                                   // KB*CBS*32 = 753,664 ushorts
  ushort* W1 = W0 + (size_t)KB*CBS*32;
  ushort* S0 = W1 + (size_t)KB*CBS*32;              // KB*NP*32 = 12,058,624 ushorts
  ushort* S1 = S0 + (size_t)KB*NP*32;
  float* pval = (float*)(S1 + (size_t)KB*NP*32);    // 16*NP floats
  int*   pidx = (int*)(pval + (size_t)16*NP);       // 16*NP ints

  // JAX: key(42) -> split -> (km, kn)
  uint32_t a0 = 0u, a1 = 2u, b0 = 1u, b1 = 3u;
  tf2x32(0u, 42u, a0, a1);
  tf2x32(0u, 42u, b0, b1);
  uint32_t km0 = a0, km1 = b0, kn0 = a1, kn1 = b1;

  cbnorm_k<<<CBS, 64, 0, stream>>>(cb, W0, W1);
  wgemm_k<<<dim3(CBS / 64, 12), 256, 0, stream>>>(proj, cb, W0, W1);
  gather_k<<<(KB * NP * 8) / 256, 256, 0, stream>>>(raw, S0, S1);
  score_k<<<dim3(CBS / 128, NP / 128), 256, 0, stream>>>(S0, S1, W0, W1, pval, pidx);
  combine_k<<<(NROW + 255) / 256, 256, 0, stream>>>(pval, pidx, len, lb);
  mask_k<<<(HMASK + 255) / 256, 256, 0, stream>>>(len, md, km0, km1);
  feats_k<<<HN / 256, 256, 0, stream>>>(aug, md, mf, kn0, kn1);
}

// Round 5
// 179.394 us; speedup vs baseline: 1.0061x; 1.0061x over previous
//
#include <hip/hip_runtime.h>
#include <cstdint>

#define B_    32
#define T_    2048
#define D_    80
#define T2_   511
#define NROW  16352      // B_*T2_
#define GK    720        // INPUT_DIM
#define CBD   512
#define CBS   1024
#define HMASK 8176       // 16352/2
#define HN    2621440    // B_*T_*D_/2
#define NP    16384      // padded rows
#define KB    23         // 736/32 k-blocks (k=720 is the norm-augment slot)

using bfrag = __attribute__((ext_vector_type(8))) short;   // 8 bf16 = 4 VGPR
using f32x4 = __attribute__((ext_vector_type(4))) float;
using s4    = __attribute__((ext_vector_type(4))) short;

__device__ inline ushort f2bf(float f){                    // RNE f32->bf16
  uint32_t u = __float_as_uint(f);
  uint32_t r = (u + 0x7FFFu + ((u >> 16) & 1u)) >> 16;
  return (ushort)r;
}
__device__ inline float bf2f(ushort h){ return __uint_as_float(((uint32_t)h) << 16); }

#define GLL16(gsrc, ldst) __builtin_amdgcn_global_load_lds( \
    (__attribute__((address_space(1))) void*)(gsrc), \
    (__attribute__((address_space(3))) void*)(ldst), 16, 0, 0)

// ---------------- threefry2x32 (exact JAX schedule) ----------------
__host__ __device__ inline uint32_t rotl_(uint32_t v, int d){ return (v<<d)|(v>>(32-d)); }

__host__ __device__ inline void tf2x32(uint32_t k0, uint32_t k1, uint32_t& x0, uint32_t& x1){
  uint32_t ks2 = k0 ^ k1 ^ 0x1BD11BDAu;
  x0 += k0; x1 += k1;
  const int r0[4] = {13,15,26,6}, r1[4] = {17,29,16,24};
#pragma unroll
  for (int i=0;i<4;i++){ x0 += x1; x1 = rotl_(x1, r0[i]); x1 ^= x0; }
  x0 += k1; x1 += ks2 + 1u;
#pragma unroll
  for (int i=0;i<4;i++){ x0 += x1; x1 = rotl_(x1, r1[i]); x1 ^= x0; }
  x0 += ks2; x1 += k0 + 2u;
#pragma unroll
  for (int i=0;i<4;i++){ x0 += x1; x1 = rotl_(x1, r0[i]); x1 ^= x0; }
  x0 += k0; x1 += k1 + 3u;
#pragma unroll
  for (int i=0;i<4;i++){ x0 += x1; x1 = rotl_(x1, r1[i]); x1 ^= x0; }
  x0 += k1; x1 += ks2 + 4u;
#pragma unroll
  for (int i=0;i<4;i++){ x0 += x1; x1 = rotl_(x1, r0[i]); x1 ^= x0; }
  x0 += ks2; x1 += k0 + 5u;
}

// XLA ErfInv32 (Giles) — matches lax.erf_inv f32
__device__ inline float erfinv_f(float x){
  float w = -log1pf(-x*x);
  float p;
  if (w < 5.0f){
    w -= 2.5f;
    p = 2.81022636e-08f;
    p = fmaf(p, w, 3.43273939e-07f);
    p = fmaf(p, w, -3.5233877e-06f);
    p = fmaf(p, w, -4.39150654e-06f);
    p = fmaf(p, w, 0.00021858087f);
    p = fmaf(p, w, -0.00125372503f);
    p = fmaf(p, w, -0.00417768164f);
    p = fmaf(p, w, 0.246640727f);
    p = fmaf(p, w, 1.50140941f);
  } else {
    w = sqrtf(w) - 3.0f;
    p = -0.000200214257f;
    p = fmaf(p, w, 0.000100950558f);
    p = fmaf(p, w, 0.00134934322f);
    p = fmaf(p, w, -0.00367342844f);
    p = fmaf(p, w, 0.00573950773f);
    p = fmaf(p, w, -0.0076224613f);
    p = fmaf(p, w, 0.00943887047f);
    p = fmaf(p, w, 1.00167406f);
    p = fmaf(p, w, 2.83297682f);
  }
  return p * x;
}

__device__ inline int label_len(int L){ return (((L - 3) / 2) - 2) / 2 + 1; }

// ---------------- kernel 1: codebook norms -> augment row (k=720) of W panels ----------------
__global__ void cbnorm_k(const float* __restrict__ cb, ushort* __restrict__ W0, ushort* __restrict__ W1){
  int c = blockIdx.x, lane = threadIdx.x;
  double s = 0.0;
  for (int k = lane; k < CBD; k += 64){ float v = cb[c*CBD + k]; s += (double)v * (double)v; }
#pragma unroll
  for (int off = 32; off; off >>= 1) s += __shfl_down(s, off);
  float nf = (float)s;
  nf = __shfl(nf, 0);
  size_t base = ((size_t)(KB-1)*CBS + c)*32;
  if (lane == 16){
    float h = -0.5f * nf;
    ushort h0 = f2bf(h); ushort h1 = f2bf(h - bf2f(h0));
    W0[base+16] = h0; W1[base+16] = h1;
  } else if (lane > 16 && lane < 32){
    W0[base+lane] = 0; W1[base+lane] = 0;
  }
}

// ---------------- kernel 2: gather stacked S -> split bf16 k-panels [kb][n][kk] ----------------
__global__ void gather_k(const float* __restrict__ raw, ushort* __restrict__ S0, ushort* __restrict__ S1){
  int idx4 = blockIdx.x * 256 + threadIdx.x;    // one thread = 4 consecutive kk
  int kk4 = idx4 & 7;
  int n   = (idx4 >> 3) & (NP - 1);
  int kb  = idx4 >> 17;                          // NP*8 = 2^17
  int b = n / T2_, t2 = n - b * T2_;
  s4 o0, o1;
#pragma unroll
  for (int j = 0; j < 4; ++j){
    int k = kb*32 + kk4*4 + j;
    float v = 0.f;
    if (n < NROW){
      if (k < GK){
        int d = k / 9, rem = k - 9*d;
        int k1 = rem / 3, k2 = rem - 3*k1;
        int tm = 4*t2 + 2*k2 + k1;
        v = raw[(b * T_ + tm) * D_ + d];
      } else if (k == GK) v = 1.f;               // norm-augment slot
    }
    ushort h0 = f2bf(v); ushort h1 = f2bf(v - bf2f(h0));
    o0[j] = (short)h0; o1[j] = (short)h1;
  }
  size_t off = ((size_t)kb*NP + n)*32 + kk4*4;
  *(s4*)&S0[off] = o0;
  *(s4*)&S1[off] = o1;
}

// ---------------- kernel 3: W = P(720x512)*cb^T -> split bf16 k-panels [kb][c][kk] ----------------
__global__ __launch_bounds__(256) void wgemm_k(const float* __restrict__ P, const float* __restrict__ cb,
                                               ushort* __restrict__ W0, ushort* __restrict__ W1){
  __shared__ float sP[16][68];
  __shared__ float sC[16][68];
  int r0 = blockIdx.y * 64, c0 = blockIdx.x * 64;
  int tid = threadIdx.x, tx = tid & 15, ty = tid >> 4;
  float acc[4][4] = {};
  for (int k0 = 0; k0 < CBD; k0 += 16){
    __syncthreads();
    {
      int r = tid >> 2, kq = tid & 3;
      int rr = r0 + r;
      float4 v = {0.f,0.f,0.f,0.f};
      if (rr < GK) v = *(const float4*)&P[rr * CBD + k0 + kq * 4];
      sP[kq*4+0][r] = v.x; sP[kq*4+1][r] = v.y; sP[kq*4+2][r] = v.z; sP[kq*4+3][r] = v.w;
      float4 w = *(const float4*)&cb[(c0 + r) * CBD + k0 + kq * 4];
      sC[kq*4+0][r] = w.x; sC[kq*4+1][r] = w.y; sC[kq*4+2][r] = w.z; sC[kq*4+3][r] = w.w;
    }
    __syncthreads();
#pragma unroll
    for (int kk = 0; kk < 16; ++kk){
      float4 a = *(const float4*)&sP[kk][ty * 4];
      float4 b = *(const float4*)&sC[kk][tx * 4];
      float av[4] = {a.x,a.y,a.z,a.w}, bv[4] = {b.x,b.y,b.z,b.w};
#pragma unroll
      for (int i = 0; i < 4; ++i)
#pragma unroll
        for (int j = 0; j < 4; ++j) acc[i][j] = fmaf(av[i], bv[j], acc[i][j]);
    }
  }
#pragma unroll
  for (int i = 0; i < 4; ++i){
    int r = r0 + ty * 4 + i;
    if (r < GK){
#pragma unroll
      for (int j = 0; j < 4; ++j){
        int c = c0 + tx * 4 + j;
        float v = acc[i][j];
        ushort h0 = f2bf(v); ushort h1 = f2bf(v - bf2f(h0));
        size_t o = ((size_t)(r >> 5) * CBS + c) * 32 + (r & 31);
        W0[o] = h0; W1[o] = h1;
      }
    }
  }
}

// ---------------- kernel 4: score = S*W via 3-pass bf16 MFMA, fused argmin ----------------
__global__ __launch_bounds__(256) void score_k(const ushort* __restrict__ S0, const ushort* __restrict__ S1,
                                               const ushort* __restrict__ W0, const ushort* __restrict__ W1,
                                               float* __restrict__ pval, int* __restrict__ pidx){
  __shared__ __align__(16) ushort lA[2][128*32];
  __shared__ __align__(16) ushort lB[2][128*32];
  int tid = threadIdx.x;
  int lane = tid & 63, wid = tid >> 6;
  int wm = wid >> 1, wn = wid & 1;        // 2x2 waves -> 64x64 tiles
  int g = lane >> 4, lr = lane & 15;
  int n0 = blockIdx.y * 128, c0 = blockIdx.x * 128;
  f32x4 acc[4][4] = {};
  for (int kb = 0; kb < KB; ++kb){
    const ushort* src; ushort* dst;
    if      (wid == 0){ src = S0 + ((size_t)kb*NP  + n0)*32; dst = &lA[0][0]; }
    else if (wid == 1){ src = S1 + ((size_t)kb*NP  + n0)*32; dst = &lA[1][0]; }
    else if (wid == 2){ src = W0 + ((size_t)kb*CBS + c0)*32; dst = &lB[0][0]; }
    else              { src = W1 + ((size_t)kb*CBS + c0)*32; dst = &lB[1][0]; }
    __syncthreads();
#pragma unroll
    for (int q = 0; q < 8; ++q)
      GLL16(src + q*512 + lane*8, dst + q*512);
    __syncthreads();
    bfrag a[2][4], bfr[2][4];
#pragma unroll
    for (int mt = 0; mt < 4; ++mt){
      int m = wm*64 + mt*16 + lr;
      a[0][mt] = *(const bfrag*)&lA[0][m*32 + g*8];
      a[1][mt] = *(const bfrag*)&lA[1][m*32 + g*8];
    }
#pragma unroll
    for (int nt = 0; nt < 4; ++nt){
      int c = wn*64 + nt*16 + lr;
      bfr[0][nt] = *(const bfrag*)&lB[0][c*32 + g*8];
      bfr[1][nt] = *(const bfrag*)&lB[1][c*32 + g*8];
    }
#pragma unroll
    for (int mt = 0; mt < 4; ++mt)
#pragma unroll
      for (int nt = 0; nt < 4; ++nt){
        acc[mt][nt] = __builtin_amdgcn_mfma_f32_16x16x32_bf16(a[0][mt], bfr[0][nt], acc[mt][nt], 0,0,0);
        acc[mt][nt] = __builtin_amdgcn_mfma_f32_16x16x32_bf16(a[0][mt], bfr[1][nt], acc[mt][nt], 0,0,0);
        acc[mt][nt] = __builtin_amdgcn_mfma_f32_16x16x32_bf16(a[1][mt], bfr[0][nt], acc[mt][nt], 0,0,0);
      }
  }
  // epilogue: dist = -2*acc (norms folded in); per-row argmin, first-index tie-break
  float bv[4][4]; int bi[4][4];
#pragma unroll
  for (int mt = 0; mt < 4; ++mt)
#pragma unroll
    for (int r = 0; r < 4; ++r){
      float best = 3.4e38f; int besti = 0;
#pragma unroll
      for (int nt = 0; nt < 4; ++nt){      // nt ascending == col ascending
        float d = -2.f * acc[mt][nt][r];
        int c = c0 + wn*64 + nt*16 + lr;
        if (d < best){ best = d; besti = c; }
      }
      bv[mt][r] = best; bi[mt][r] = besti;
    }
#pragma unroll
  for (int off = 1; off < 16; off <<= 1){
#pragma unroll
    for (int mt = 0; mt < 4; ++mt)
#pragma unroll
      for (int r = 0; r < 4; ++r){
        float ov = __shfl_xor(bv[mt][r], off);
        int   oi = __shfl_xor(bi[mt][r], off);
        if (ov < bv[mt][r] || (ov == bv[mt][r] && oi < bi[mt][r])){ bv[mt][r] = ov; bi[mt][r] = oi; }
      }
  }
  if (lr == 0){
    int p = blockIdx.x*2 + wn;
#pragma unroll
    for (int mt = 0; mt < 4; ++mt)
#pragma unroll
      for (int r = 0; r < 4; ++r){
        int n = n0 + wm*64 + mt*16 + g*4 + r;
        pval[(size_t)p*NP + n] = bv[mt][r];
        pidx[(size_t)p*NP + n] = bi[mt][r];
      }
  }
}

// ---------------- kernel 5: combine 16 partial argmins -> labels ----------------
__global__ void combine_k(const float* __restrict__ pval, const int* __restrict__ pidx,
                          const int* __restrict__ len, float* __restrict__ lb){
  int n = blockIdx.x * 256 + threadIdx.x;
  if (n >= NROW) return;
  float bv = pval[n]; int bi = pidx[n];
#pragma unroll
  for (int p = 1; p < 16; ++p){
    float v = pval[(size_t)p*NP + n]; int ii = pidx[(size_t)p*NP + n];
    if (v < bv || (v == bv && ii < bi)){ bv = v; bi = ii; }
  }
  int b = n / T2_, t2 = n - b * T2_;
  lb[n] = (t2 < label_len(len[b])) ? (float)(bi + 1) : 0.f;
}

// ---------------- kernel 6: mask (threefry uniform, bit-exact) ----------------
__device__ inline void emit_mask(const int* len, float* md, int i, uint32_t bits){
  float u = __uint_as_float((bits >> 9) | 0x3F800000u) - 1.0f;
  int b = i / T2_, t2 = i - b * T2_;
  bool m = (u < 0.1f) && (t2 < label_len(len[b]));
  md[i] = m ? 1.0f : 0.0f;
}

__global__ void mask_k(const int* __restrict__ len, float* __restrict__ md, uint32_t km0, uint32_t km1){
  int j = blockIdx.x * 256 + threadIdx.x;
  if (j >= HMASK) return;
  uint32_t x0 = (uint32_t)j, x1 = (uint32_t)(j + HMASK);
  tf2x32(km0, km1, x0, x1);
  emit_mask(len, md, j, x0);
  emit_mask(len, md, j + HMASK, x1);
}

// ---------------- kernel 7: masked_feats (threefry normal, bit-exact bits) ----------------
__device__ inline void emit_feat(const float* aug, const float* md, float* mf, int i, uint32_t bits){
  int tabs = i / D_;
  int t = tabs & (T_ - 1);
  int b = i / (D_ * T_);
  int lo = (t < 3) ? 0 : ((t - 3) >> 2);
  int hi = t >> 2; if (hi > T2_ - 1) hi = T2_ - 1;
  bool m = false;
  for (int t2 = lo; t2 <= hi; ++t2) m = m || (md[b * T2_ + t2] != 0.f);
  float v;
  if (m){
    float f = __uint_as_float((bits >> 9) | 0x3F800000u) - 1.0f;
    const float LOV = -0.99999994f;
    float u = fmaf(f, 2.0f, LOV);
    u = fmaxf(LOV, u);
    v = 0.1f * (1.41421356f * erfinv_f(u));
  } else {
    v = aug[i];
  }
  mf[i] = v;
}

__global__ void feats_k(const float* __restrict__ aug, const float* __restrict__ md,
                        float* __restrict__ mf, uint32_t kn0, uint32_t kn1){
  int j = blockIdx.x * 256 + threadIdx.x;
  uint32_t x0 = (uint32_t)j, x1 = (uint32_t)(j + HN);
  tf2x32(kn0, kn1, x0, x1);
  emit_feat(aug, md, mf, j, x0);
  emit_feat(aug, md, mf, j + HN, x1);
}

// ---------------- host ----------------
extern "C" void kernel_launch(void* const* d_in, const int* in_sizes, int n_in,
                              void* d_out, int out_size, void* d_ws, size_t ws_size,
                              hipStream_t stream){
  const float* raw  = (const float*)d_in[0];
  const float* aug  = (const float*)d_in[1];
  const int*   len  = (const int*)  d_in[2];
  const float* proj = (const float*)d_in[3];
  const float* cb   = (const float*)d_in[4];

  float* out = (float*)d_out;
  float* mf  = out;                       // (B,T,D)   5,242,880
  float* lb  = out + 5242880;             // (1,B,T2)     16,352
  float* md  = out + 5259232;             // (B,T2)       16,352

  ushort* w  = (ushort*)d_ws;
  ushort* W0 = w;                                   // KB*CBS*32 = 753,664 ushorts
  ushort* W1 = W0 + (size_t)KB*CBS*32;
  ushort* S0 = W1 + (size_t)KB*CBS*32;              // KB*NP*32 = 12,058,624 ushorts
  ushort* S1 = S0 + (size_t)KB*NP*32;
  float* pval = (float*)(S1 + (size_t)KB*NP*32);    // 16*NP floats
  int*   pidx = (int*)(pval + (size_t)16*NP);       // 16*NP ints

  // JAX: key(42) -> split -> (km, kn)
  uint32_t a0 = 0u, a1 = 2u, b0 = 1u, b1 = 3u;
  tf2x32(0u, 42u, a0, a1);
  tf2x32(0u, 42u, b0, b1);
  uint32_t km0 = a0, km1 = b0, kn0 = a1, kn1 = b1;

  cbnorm_k<<<CBS, 64, 0, stream>>>(cb, W0, W1);
  wgemm_k<<<dim3(CBS / 64, 12), 256, 0, stream>>>(proj, cb, W0, W1);
  gather_k<<<(KB * NP * 8) / 256, 256, 0, stream>>>(raw, S0, S1);
  score_k<<<dim3(CBS / 128, NP / 128), 256, 0, stream>>>(S0, S1, W0, W1, pval, pidx);
  combine_k<<<(NROW + 255) / 256, 256, 0, stream>>>(pval, pidx, len, lb);
  mask_k<<<(HMASK + 255) / 256, 256, 0, stream>>>(len, md, km0, km1);
  feats_k<<<HN / 256, 256, 0, stream>>>(aug, md, mf, kn0, kn1);
}

// Round 6
// 160.998 us; speedup vs baseline: 1.1210x; 1.1143x over previous
//
#include <hip/hip_runtime.h>
#include <cstdint>

#define B_    32
#define T_    2048
#define D_    80
#define T2_   511
#define NROW  16352      // B_*T2_
#define GK    720        // INPUT_DIM
#define CBD   512
#define CBS   1024
#define HMASK 8176       // 16352/2
#define HN    2621440    // B_*T_*D_/2
#define NP    16384      // padded rows
#define KB    23         // 736/32 k-blocks (k=720 is the norm-augment slot)

using bfrag = __attribute__((ext_vector_type(8))) short;   // 8 bf16 = 4 VGPR
using f32x4 = __attribute__((ext_vector_type(4))) float;
using s4    = __attribute__((ext_vector_type(4))) short;

__device__ inline ushort f2bf(float f){                    // RNE f32->bf16
  uint32_t u = __float_as_uint(f);
  uint32_t r = (u + 0x7FFFu + ((u >> 16) & 1u)) >> 16;
  return (ushort)r;
}
__device__ inline float bf2f(ushort h){ return __uint_as_float(((uint32_t)h) << 16); }

#define GLL16(gsrc, ldst) __builtin_amdgcn_global_load_lds( \
    (__attribute__((address_space(1))) void*)(gsrc), \
    (__attribute__((address_space(3))) void*)(ldst), 16, 0, 0)

// ---------------- threefry2x32 (exact JAX schedule) ----------------
__host__ __device__ inline uint32_t rotl_(uint32_t v, int d){ return (v<<d)|(v>>(32-d)); }

__host__ __device__ inline void tf2x32(uint32_t k0, uint32_t k1, uint32_t& x0, uint32_t& x1){
  uint32_t ks2 = k0 ^ k1 ^ 0x1BD11BDAu;
  x0 += k0; x1 += k1;
  const int r0[4] = {13,15,26,6}, r1[4] = {17,29,16,24};
#pragma unroll
  for (int i=0;i<4;i++){ x0 += x1; x1 = rotl_(x1, r0[i]); x1 ^= x0; }
  x0 += k1; x1 += ks2 + 1u;
#pragma unroll
  for (int i=0;i<4;i++){ x0 += x1; x1 = rotl_(x1, r1[i]); x1 ^= x0; }
  x0 += ks2; x1 += k0 + 2u;
#pragma unroll
  for (int i=0;i<4;i++){ x0 += x1; x1 = rotl_(x1, r0[i]); x1 ^= x0; }
  x0 += k0; x1 += k1 + 3u;
#pragma unroll
  for (int i=0;i<4;i++){ x0 += x1; x1 = rotl_(x1, r1[i]); x1 ^= x0; }
  x0 += k1; x1 += ks2 + 4u;
#pragma unroll
  for (int i=0;i<4;i++){ x0 += x1; x1 = rotl_(x1, r0[i]); x1 ^= x0; }
  x0 += ks2; x1 += k0 + 5u;
}

// XLA ErfInv32 (Giles) — matches lax.erf_inv f32
__device__ inline float erfinv_f(float x){
  float w = -log1pf(-x*x);
  float p;
  if (w < 5.0f){
    w -= 2.5f;
    p = 2.81022636e-08f;
    p = fmaf(p, w, 3.43273939e-07f);
    p = fmaf(p, w, -3.5233877e-06f);
    p = fmaf(p, w, -4.39150654e-06f);
    p = fmaf(p, w, 0.00021858087f);
    p = fmaf(p, w, -0.00125372503f);
    p = fmaf(p, w, -0.00417768164f);
    p = fmaf(p, w, 0.246640727f);
    p = fmaf(p, w, 1.50140941f);
  } else {
    w = sqrtf(w) - 3.0f;
    p = -0.000200214257f;
    p = fmaf(p, w, 0.000100950558f);
    p = fmaf(p, w, 0.00134934322f);
    p = fmaf(p, w, -0.00367342844f);
    p = fmaf(p, w, 0.00573950773f);
    p = fmaf(p, w, -0.0076224613f);
    p = fmaf(p, w, 0.00943887047f);
    p = fmaf(p, w, 1.00167406f);
    p = fmaf(p, w, 2.83297682f);
  }
  return p * x;
}

__device__ inline int label_len(int L){ return (((L - 3) / 2) - 2) / 2 + 1; }

// ---------------- kernel 1: codebook norms -> augment row (k=720) of W panels ----------------
__global__ void cbnorm_k(const float* __restrict__ cb, ushort* __restrict__ W0, ushort* __restrict__ W1){
  int c = blockIdx.x, lane = threadIdx.x;
  double s = 0.0;
  for (int k = lane; k < CBD; k += 64){ float v = cb[c*CBD + k]; s += (double)v * (double)v; }
#pragma unroll
  for (int off = 32; off; off >>= 1) s += __shfl_down(s, off);
  float nf = (float)s;
  nf = __shfl(nf, 0);
  size_t base = ((size_t)(KB-1)*CBS + c)*32;
  int sw = ((c >> 1) & 3) << 3;
  if (lane == 16){
    float h = -0.5f * nf;
    ushort h0 = f2bf(h); ushort h1 = f2bf(h - bf2f(h0));
    W0[base + (16 ^ sw)] = h0; W1[base + (16 ^ sw)] = h1;
  } else if (lane > 16 && lane < 32){
    W0[base + (lane ^ sw)] = 0; W1[base + (lane ^ sw)] = 0;
  }
}

// ---------------- kernel 2: gather stacked S -> split bf16 k-panels [kb][n][kk-swz] ----------------
__global__ void gather_k(const float* __restrict__ raw, ushort* __restrict__ S0, ushort* __restrict__ S1){
  int idx4 = blockIdx.x * 256 + threadIdx.x;    // one thread = 4 consecutive kk
  int kk4 = idx4 & 7;
  int n   = (idx4 >> 3) & (NP - 1);
  int kb  = idx4 >> 17;                          // NP*8 = 2^17
  int b = n / T2_, t2 = n - b * T2_;
  s4 o0, o1;
#pragma unroll
  for (int j = 0; j < 4; ++j){
    int k = kb*32 + kk4*4 + j;
    float v = 0.f;
    if (n < NROW){
      if (k < GK){
        int d = k / 9, rem = k - 9*d;
        int k1 = rem / 3, k2 = rem - 3*k1;
        int tm = 4*t2 + 2*k2 + k1;
        v = raw[(b * T_ + tm) * D_ + d];
      } else if (k == GK) v = 1.f;               // norm-augment slot
    }
    ushort h0 = f2bf(v); ushort h1 = f2bf(v - bf2f(h0));
    o0[j] = (short)h0; o1[j] = (short)h1;
  }
  int kk4s = kk4 ^ ((((n >> 1)) & 3) << 1);      // 16B-granule XOR swizzle
  size_t off = ((size_t)kb*NP + n)*32 + kk4s*4;
  *(s4*)&S0[off] = o0;
  *(s4*)&S1[off] = o1;
}

// ---------------- kernel 3a: Wp[kz] = P(720x512)*cb^T, split-K x4 (fp32) ----------------
__global__ __launch_bounds__(256) void wgemm_k(const float* __restrict__ P, const float* __restrict__ cb,
                                               float* __restrict__ Wp){
  __shared__ float sP[16][68];
  __shared__ float sC[16][68];
  int r0 = blockIdx.y * 64, c0 = blockIdx.x * 64;
  int kz = blockIdx.z;
  int tid = threadIdx.x, tx = tid & 15, ty = tid >> 4;
  float acc[4][4] = {};
  for (int k0 = kz * 128; k0 < kz * 128 + 128; k0 += 16){
    __syncthreads();
    {
      int r = tid >> 2, kq = tid & 3;
      int rr = r0 + r;
      float4 v = {0.f,0.f,0.f,0.f};
      if (rr < GK) v = *(const float4*)&P[rr * CBD + k0 + kq * 4];
      sP[kq*4+0][r] = v.x; sP[kq*4+1][r] = v.y; sP[kq*4+2][r] = v.z; sP[kq*4+3][r] = v.w;
      float4 w = *(const float4*)&cb[(c0 + r) * CBD + k0 + kq * 4];
      sC[kq*4+0][r] = w.x; sC[kq*4+1][r] = w.y; sC[kq*4+2][r] = w.z; sC[kq*4+3][r] = w.w;
    }
    __syncthreads();
#pragma unroll
    for (int kk = 0; kk < 16; ++kk){
      float4 a = *(const float4*)&sP[kk][ty * 4];
      float4 b = *(const float4*)&sC[kk][tx * 4];
      float av[4] = {a.x,a.y,a.z,a.w}, bv[4] = {b.x,b.y,b.z,b.w};
#pragma unroll
      for (int i = 0; i < 4; ++i)
#pragma unroll
        for (int j = 0; j < 4; ++j) acc[i][j] = fmaf(av[i], bv[j], acc[i][j]);
    }
  }
#pragma unroll
  for (int i = 0; i < 4; ++i){
    int r = r0 + ty * 4 + i;
    if (r < GK){
      float4 o; o.x = acc[i][0]; o.y = acc[i][1]; o.z = acc[i][2]; o.w = acc[i][3];
      *(float4*)&Wp[((size_t)kz * GK + r) * CBS + c0 + tx * 4] = o;
    }
  }
}

// ---------------- kernel 3b: reduce split-K, split bf16, write swizzled panels ----------------
__global__ void wreduce_k(const float* __restrict__ Wp, ushort* __restrict__ W0, ushort* __restrict__ W1){
  int idx = blockIdx.x * 256 + threadIdx.x;      // GK*CBS total
  int r = idx >> 10, c = idx & (CBS - 1);
  float v = Wp[(size_t)r * CBS + c]
          + Wp[((size_t)GK + r) * CBS + c]
          + Wp[((size_t)2*GK + r) * CBS + c]
          + Wp[((size_t)3*GK + r) * CBS + c];
  ushort h0 = f2bf(v); ushort h1 = f2bf(v - bf2f(h0));
  size_t o = ((size_t)(r >> 5) * CBS + c) * 32 + ((r & 31) ^ (((c >> 1) & 3) << 3));
  W0[o] = h0; W1[o] = h1;
}

// ---------------- kernel 4: score = S*W via 3-pass bf16 MFMA, dbuf + swizzle + XCD ----------------
__global__ __launch_bounds__(256) void score_k(const ushort* __restrict__ S0, const ushort* __restrict__ S1,
                                               const ushort* __restrict__ W0, const ushort* __restrict__ W1,
                                               float* __restrict__ pval, int* __restrict__ pidx){
  __shared__ __align__(16) ushort lA[2][2][128*32];   // [buf][split][row*32]
  __shared__ __align__(16) ushort lB[2][2][128*32];
  int tid = threadIdx.x;
  int lane = tid & 63, wid = tid >> 6;
  int wm = wid >> 1, wn = wid & 1;        // 2x2 waves -> 64x64 tiles
  int g = lane >> 4, lr = lane & 15;
  // XCD-aware decode: col-blocks of one row-panel land on one XCD
  int id = blockIdx.x;
  int xcd = id & 7, slot = id >> 3;
  int cidx = slot & 7, ridx = (xcd << 4) | (slot >> 3);
  int n0 = ridx * 128, c0 = cidx * 128;

  // per-wave staging source for a given kb
  const ushort* base;
  size_t stride32;
  if      (wid == 0){ base = S0 + (size_t)n0*32; stride32 = (size_t)NP*32; }
  else if (wid == 1){ base = S1 + (size_t)n0*32; stride32 = (size_t)NP*32; }
  else if (wid == 2){ base = W0 + (size_t)c0*32; stride32 = (size_t)CBS*32; }
  else              { base = W1 + (size_t)c0*32; stride32 = (size_t)CBS*32; }
  ushort* dstA[2] = { &lA[0][wid&1][0], &lA[1][wid&1][0] };
  ushort* dstB[2] = { &lB[0][wid&1][0], &lB[1][wid&1][0] };

  f32x4 acc[4][4] = {};
  // prologue: stage kb=0 into buf 0
  {
    const ushort* src = base;
    ushort* dst = (wid < 2) ? dstA[0] : dstB[0];
#pragma unroll
    for (int q = 0; q < 8; ++q) GLL16(src + q*512 + lane*8, dst + q*512);
  }
  __syncthreads();
  int buf = 0;
  for (int kb = 0; kb < KB; ++kb){
    if (kb + 1 < KB){                         // issue next-tile loads BEFORE compute
      const ushort* src = base + (size_t)(kb+1) * stride32;
      ushort* dst = (wid < 2) ? dstA[buf^1] : dstB[buf^1];
#pragma unroll
      for (int q = 0; q < 8; ++q) GLL16(src + q*512 + lane*8, dst + q*512);
    }
    bfrag a[2][4], bfr[2][4];
#pragma unroll
    for (int mt = 0; mt < 4; ++mt){
      int m = wm*64 + mt*16 + lr;
      int sw = (g ^ ((m >> 1) & 3)) * 8;
      a[0][mt] = *(const bfrag*)&lA[buf][0][m*32 + sw];
      a[1][mt] = *(const bfrag*)&lA[buf][1][m*32 + sw];
    }
#pragma unroll
    for (int nt = 0; nt < 4; ++nt){
      int c = wn*64 + nt*16 + lr;
      int sw = (g ^ ((c >> 1) & 3)) * 8;
      bfr[0][nt] = *(const bfrag*)&lB[buf][0][c*32 + sw];
      bfr[1][nt] = *(const bfrag*)&lB[buf][1][c*32 + sw];
    }
#pragma unroll
    for (int mt = 0; mt < 4; ++mt)
#pragma unroll
      for (int nt = 0; nt < 4; ++nt){
        acc[mt][nt] = __builtin_amdgcn_mfma_f32_16x16x32_bf16(a[0][mt], bfr[0][nt], acc[mt][nt], 0,0,0);
        acc[mt][nt] = __builtin_amdgcn_mfma_f32_16x16x32_bf16(a[0][mt], bfr[1][nt], acc[mt][nt], 0,0,0);
        acc[mt][nt] = __builtin_amdgcn_mfma_f32_16x16x32_bf16(a[1][mt], bfr[0][nt], acc[mt][nt], 0,0,0);
      }
    __syncthreads();                          // drains vmcnt(0): next buffer ready
    buf ^= 1;
  }
  // epilogue: dist = -2*acc (norms folded in); per-row argmin, first-index tie-break
  float bv[4][4]; int bi[4][4];
#pragma unroll
  for (int mt = 0; mt < 4; ++mt)
#pragma unroll
    for (int r = 0; r < 4; ++r){
      float best = 3.4e38f; int besti = 0;
#pragma unroll
      for (int nt = 0; nt < 4; ++nt){      // nt ascending == col ascending
        float d = -2.f * acc[mt][nt][r];
        int c = c0 + wn*64 + nt*16 + lr;
        if (d < best){ best = d; besti = c; }
      }
      bv[mt][r] = best; bi[mt][r] = besti;
    }
#pragma unroll
  for (int off = 1; off < 16; off <<= 1){
#pragma unroll
    for (int mt = 0; mt < 4; ++mt)
#pragma unroll
      for (int r = 0; r < 4; ++r){
        float ov = __shfl_xor(bv[mt][r], off);
        int   oi = __shfl_xor(bi[mt][r], off);
        if (ov < bv[mt][r] || (ov == bv[mt][r] && oi < bi[mt][r])){ bv[mt][r] = ov; bi[mt][r] = oi; }
      }
  }
  if (lr == 0){
    int p = cidx*2 + wn;
#pragma unroll
    for (int mt = 0; mt < 4; ++mt)
#pragma unroll
      for (int r = 0; r < 4; ++r){
        int n = n0 + wm*64 + mt*16 + g*4 + r;
        pval[(size_t)p*NP + n] = bv[mt][r];
        pidx[(size_t)p*NP + n] = bi[mt][r];
      }
  }
}

// ---------------- kernel 5: combine 16 partial argmins -> labels ----------------
__global__ void combine_k(const float* __restrict__ pval, const int* __restrict__ pidx,
                          const int* __restrict__ len, float* __restrict__ lb){
  int n = blockIdx.x * 256 + threadIdx.x;
  if (n >= NROW) return;
  float bv = pval[n]; int bi = pidx[n];
#pragma unroll
  for (int p = 1; p < 16; ++p){
    float v = pval[(size_t)p*NP + n]; int ii = pidx[(size_t)p*NP + n];
    if (v < bv || (v == bv && ii < bi)){ bv = v; bi = ii; }
  }
  int b = n / T2_, t2 = n - b * T2_;
  lb[n] = (t2 < label_len(len[b])) ? (float)(bi + 1) : 0.f;
}

// ---------------- kernel 6: mask (threefry uniform, bit-exact) ----------------
__device__ inline void emit_mask(const int* len, float* md, int i, uint32_t bits){
  float u = __uint_as_float((bits >> 9) | 0x3F800000u) - 1.0f;
  int b = i / T2_, t2 = i - b * T2_;
  bool m = (u < 0.1f) && (t2 < label_len(len[b]));
  md[i] = m ? 1.0f : 0.0f;
}

__global__ void mask_k(const int* __restrict__ len, float* __restrict__ md, uint32_t km0, uint32_t km1){
  int j = blockIdx.x * 256 + threadIdx.x;
  if (j >= HMASK) return;
  uint32_t x0 = (uint32_t)j, x1 = (uint32_t)(j + HMASK);
  tf2x32(km0, km1, x0, x1);
  emit_mask(len, md, j, x0);
  emit_mask(len, md, j + HMASK, x1);
}

// ---------------- kernel 7: masked_feats (threefry normal, bit-exact bits) ----------------
__device__ inline void emit_feat(const float* aug, const float* md, float* mf, int i, uint32_t bits){
  int tabs = i / D_;
  int t = tabs & (T_ - 1);
  int b = i / (D_ * T_);
  int lo = (t < 3) ? 0 : ((t - 3) >> 2);
  int hi = t >> 2; if (hi > T2_ - 1) hi = T2_ - 1;
  bool m = false;
  for (int t2 = lo; t2 <= hi; ++t2) m = m || (md[b * T2_ + t2] != 0.f);
  float v;
  if (m){
    float f = __uint_as_float((bits >> 9) | 0x3F800000u) - 1.0f;
    const float LOV = -0.99999994f;
    float u = fmaf(f, 2.0f, LOV);
    u = fmaxf(LOV, u);
    v = 0.1f * (1.41421356f * erfinv_f(u));
  } else {
    v = aug[i];
  }
  mf[i] = v;
}

__global__ void feats_k(const float* __restrict__ aug, const float* __restrict__ md,
                        float* __restrict__ mf, uint32_t kn0, uint32_t kn1){
  int j = blockIdx.x * 256 + threadIdx.x;
  uint32_t x0 = (uint32_t)j, x1 = (uint32_t)(j + HN);
  tf2x32(kn0, kn1, x0, x1);
  emit_feat(aug, md, mf, j, x0);
  emit_feat(aug, md, mf, j + HN, x1);
}

// ---------------- host ----------------
extern "C" void kernel_launch(void* const* d_in, const int* in_sizes, int n_in,
                              void* d_out, int out_size, void* d_ws, size_t ws_size,
                              hipStream_t stream){
  const float* raw  = (const float*)d_in[0];
  const float* aug  = (const float*)d_in[1];
  const int*   len  = (const int*)  d_in[2];
  const float* proj = (const float*)d_in[3];
  const float* cb   = (const float*)d_in[4];

  float* out = (float*)d_out;
  float* mf  = out;                       // (B,T,D)   5,242,880
  float* lb  = out + 5242880;             // (1,B,T2)     16,352
  float* md  = out + 5259232;             // (B,T2)       16,352

  ushort* w  = (ushort*)d_ws;
  ushort* W0 = w;                                   // KB*CBS*32 = 753,664 ushorts
  ushort* W1 = W0 + (size_t)KB*CBS*32;
  ushort* S0 = W1 + (size_t)KB*CBS*32;              // KB*NP*32 = 12,058,624 ushorts
  ushort* S1 = S0 + (size_t)KB*NP*32;
  float* pval = (float*)(S1 + (size_t)KB*NP*32);    // 16*NP floats
  int*   pidx = (int*)(pval + (size_t)16*NP);       // 16*NP ints
  float* Wp   = (float*)(pidx + (size_t)16*NP);     // 4*GK*CBS floats = 11.8MB

  // JAX: key(42) -> split -> (km, kn)
  uint32_t a0 = 0u, a1 = 2u, b0 = 1u, b1 = 3u;
  tf2x32(0u, 42u, a0, a1);
  tf2x32(0u, 42u, b0, b1);
  uint32_t km0 = a0, km1 = b0, kn0 = a1, kn1 = b1;

  cbnorm_k<<<CBS, 64, 0, stream>>>(cb, W0, W1);
  wgemm_k<<<dim3(CBS / 64, 12, 4), 256, 0, stream>>>(proj, cb, Wp);
  wreduce_k<<<(GK * CBS) / 256, 256, 0, stream>>>(Wp, W0, W1);
  gather_k<<<(KB * NP * 8) / 256, 256, 0, stream>>>(raw, S0, S1);
  score_k<<<1024, 256, 0, stream>>>(S0, S1, W0, W1, pval, pidx);
  combine_k<<<(NROW + 255) / 256, 256, 0, stream>>>(pval, pidx, len, lb);
  mask_k<<<(HMASK + 255) / 256, 256, 0, stream>>>(len, md, km0, km1);
  feats_k<<<HN / 256, 256, 0, stream>>>(aug, md, mf, kn0, kn1);
}

// Round 7
// 151.674 us; speedup vs baseline: 1.1899x; 1.0615x over previous
//
#include <hip/hip_runtime.h>
#include <cstdint>

#define B_    32
#define T_    2048
#define D_    80
#define T2_   511
#define NROW  16352      // B_*T2_
#define GK    720        // INPUT_DIM
#define CBD   512
#define CBS   1024
#define HMASK 8176       // 16352/2
#define HN    2621440    // B_*T_*D_/2
#define NP    16384      // padded rows
#define KB    23         // 736/32 k-blocks (k=720 is the norm-augment slot)

using bfrag = __attribute__((ext_vector_type(8))) short;   // 8 bf16 = 4 VGPR
using f32x4 = __attribute__((ext_vector_type(4))) float;
using s4    = __attribute__((ext_vector_type(4))) short;
using s8    = __attribute__((ext_vector_type(8))) short;

__device__ inline ushort f2bf(float f){                    // RNE f32->bf16
  uint32_t u = __float_as_uint(f);
  uint32_t r = (u + 0x7FFFu + ((u >> 16) & 1u)) >> 16;
  return (ushort)r;
}
__device__ inline float bf2f(ushort h){ return __uint_as_float(((uint32_t)h) << 16); }

#define GLL16(gsrc, ldst) __builtin_amdgcn_global_load_lds( \
    (__attribute__((address_space(1))) void*)(gsrc), \
    (__attribute__((address_space(3))) void*)(ldst), 16, 0, 0)

// ---------------- threefry2x32 (exact JAX schedule) ----------------
__host__ __device__ inline uint32_t rotl_(uint32_t v, int d){ return (v<<d)|(v>>(32-d)); }

__host__ __device__ inline void tf2x32(uint32_t k0, uint32_t k1, uint32_t& x0, uint32_t& x1){
  uint32_t ks2 = k0 ^ k1 ^ 0x1BD11BDAu;
  x0 += k0; x1 += k1;
  const int r0[4] = {13,15,26,6}, r1[4] = {17,29,16,24};
#pragma unroll
  for (int i=0;i<4;i++){ x0 += x1; x1 = rotl_(x1, r0[i]); x1 ^= x0; }
  x0 += k1; x1 += ks2 + 1u;
#pragma unroll
  for (int i=0;i<4;i++){ x0 += x1; x1 = rotl_(x1, r1[i]); x1 ^= x0; }
  x0 += ks2; x1 += k0 + 2u;
#pragma unroll
  for (int i=0;i<4;i++){ x0 += x1; x1 = rotl_(x1, r0[i]); x1 ^= x0; }
  x0 += k0; x1 += k1 + 3u;
#pragma unroll
  for (int i=0;i<4;i++){ x0 += x1; x1 = rotl_(x1, r1[i]); x1 ^= x0; }
  x0 += k1; x1 += ks2 + 4u;
#pragma unroll
  for (int i=0;i<4;i++){ x0 += x1; x1 = rotl_(x1, r0[i]); x1 ^= x0; }
  x0 += ks2; x1 += k0 + 5u;
}

// XLA ErfInv32 (Giles) — matches lax.erf_inv f32
__device__ inline float erfinv_f(float x){
  float w = -log1pf(-x*x);
  float p;
  if (w < 5.0f){
    w -= 2.5f;
    p = 2.81022636e-08f;
    p = fmaf(p, w, 3.43273939e-07f);
    p = fmaf(p, w, -3.5233877e-06f);
    p = fmaf(p, w, -4.39150654e-06f);
    p = fmaf(p, w, 0.00021858087f);
    p = fmaf(p, w, -0.00125372503f);
    p = fmaf(p, w, -0.00417768164f);
    p = fmaf(p, w, 0.246640727f);
    p = fmaf(p, w, 1.50140941f);
  } else {
    w = sqrtf(w) - 3.0f;
    p = -0.000200214257f;
    p = fmaf(p, w, 0.000100950558f);
    p = fmaf(p, w, 0.00134934322f);
    p = fmaf(p, w, -0.00367342844f);
    p = fmaf(p, w, 0.00573950773f);
    p = fmaf(p, w, -0.0076224613f);
    p = fmaf(p, w, 0.00943887047f);
    p = fmaf(p, w, 1.00167406f);
    p = fmaf(p, w, 2.83297682f);
  }
  return p * x;
}

__device__ inline int label_len(int L){ return (((L - 3) / 2) - 2) / 2 + 1; }

// ---------------- kernel 1: codebook norms -> augment row (k=720) of W panels ----------------
__global__ void cbnorm_k(const float* __restrict__ cb, ushort* __restrict__ W0, ushort* __restrict__ W1){
  int c = blockIdx.x, lane = threadIdx.x;
  double s = 0.0;
  for (int k = lane; k < CBD; k += 64){ float v = cb[c*CBD + k]; s += (double)v * (double)v; }
#pragma unroll
  for (int off = 32; off; off >>= 1) s += __shfl_down(s, off);
  float nf = (float)s;
  nf = __shfl(nf, 0);
  size_t base = ((size_t)(KB-1)*CBS + c)*32;
  int sw = ((c >> 1) & 3) << 3;
  if (lane == 16){
    float h = -0.5f * nf;
    ushort h0 = f2bf(h); ushort h1 = f2bf(h - bf2f(h0));
    W0[base + (16 ^ sw)] = h0; W1[base + (16 ^ sw)] = h1;
  } else if (lane > 16 && lane < 32){
    W0[base + (lane ^ sw)] = 0; W1[base + (lane ^ sw)] = 0;
  }
}

// ---------------- kernel 2: gather stacked S -> split bf16 k-panels [kb][n][kk-swz], 16B stores ----------------
__global__ void gather_k(const float* __restrict__ raw, ushort* __restrict__ S0, ushort* __restrict__ S1){
  int idx = blockIdx.x * 256 + threadIdx.x;      // one thread = one 16B granule (8 k)
  int g  = idx & 3;
  int n  = (idx >> 2) & (NP - 1);
  int kb = idx >> 16;                            // NP*4 = 2^16
  int b = n / T2_, t2 = n - b * T2_;
  s8 o0, o1;
#pragma unroll
  for (int j = 0; j < 8; ++j){
    int k = kb*32 + g*8 + j;
    float v = 0.f;
    if (n < NROW){
      if (k < GK){
        int d = k / 9, rem = k - 9*d;
        int k1 = rem / 3, k2 = rem - 3*k1;
        int tm = 4*t2 + 2*k2 + k1;
        v = raw[(b * T_ + tm) * D_ + d];
      } else if (k == GK) v = 1.f;               // norm-augment slot
    }
    ushort h0 = f2bf(v); ushort h1 = f2bf(v - bf2f(h0));
    o0[j] = (short)h0; o1[j] = (short)h1;
  }
  int gs = g ^ ((n >> 1) & 3);                   // 16B-granule XOR swizzle
  size_t off = ((size_t)kb*NP + n)*32 + gs*8;
  *(s8*)&S0[off] = o0;
  *(s8*)&S1[off] = o1;
}

// ---------------- kernel 3a: Wp[kz] = P(720x512)*cb^T, split-K x4 (fp32) ----------------
__global__ __launch_bounds__(256) void wgemm_k(const float* __restrict__ P, const float* __restrict__ cb,
                                               float* __restrict__ Wp){
  __shared__ float sP[16][68];
  __shared__ float sC[16][68];
  int r0 = blockIdx.y * 64, c0 = blockIdx.x * 64;
  int kz = blockIdx.z;
  int tid = threadIdx.x, tx = tid & 15, ty = tid >> 4;
  float acc[4][4] = {};
  for (int k0 = kz * 128; k0 < kz * 128 + 128; k0 += 16){
    __syncthreads();
    {
      int r = tid >> 2, kq = tid & 3;
      int rr = r0 + r;
      float4 v = {0.f,0.f,0.f,0.f};
      if (rr < GK) v = *(const float4*)&P[rr * CBD + k0 + kq * 4];
      sP[kq*4+0][r] = v.x; sP[kq*4+1][r] = v.y; sP[kq*4+2][r] = v.z; sP[kq*4+3][r] = v.w;
      float4 w = *(const float4*)&cb[(c0 + r) * CBD + k0 + kq * 4];
      sC[kq*4+0][r] = w.x; sC[kq*4+1][r] = w.y; sC[kq*4+2][r] = w.z; sC[kq*4+3][r] = w.w;
    }
    __syncthreads();
#pragma unroll
    for (int kk = 0; kk < 16; ++kk){
      float4 a = *(const float4*)&sP[kk][ty * 4];
      float4 b = *(const float4*)&sC[kk][tx * 4];
      float av[4] = {a.x,a.y,a.z,a.w}, bv[4] = {b.x,b.y,b.z,b.w};
#pragma unroll
      for (int i = 0; i < 4; ++i)
#pragma unroll
        for (int j = 0; j < 4; ++j) acc[i][j] = fmaf(av[i], bv[j], acc[i][j]);
    }
  }
#pragma unroll
  for (int i = 0; i < 4; ++i){
    int r = r0 + ty * 4 + i;
    if (r < GK){
      float4 o; o.x = acc[i][0]; o.y = acc[i][1]; o.z = acc[i][2]; o.w = acc[i][3];
      *(float4*)&Wp[((size_t)kz * GK + r) * CBS + c0 + tx * 4] = o;
    }
  }
}

// ---------------- kernel 3b: reduce split-K, split bf16, write swizzled panels ----------------
__global__ void wreduce_k(const float* __restrict__ Wp, ushort* __restrict__ W0, ushort* __restrict__ W1){
  int idx = blockIdx.x * 256 + threadIdx.x;      // GK*CBS total
  int r = idx >> 10, c = idx & (CBS - 1);
  float v = Wp[(size_t)r * CBS + c]
          + Wp[((size_t)GK + r) * CBS + c]
          + Wp[((size_t)2*GK + r) * CBS + c]
          + Wp[((size_t)3*GK + r) * CBS + c];
  ushort h0 = f2bf(v); ushort h1 = f2bf(v - bf2f(h0));
  size_t o = ((size_t)(r >> 5) * CBS + c) * 32 + ((r & 31) ^ (((c >> 1) & 3) << 3));
  W0[o] = h0; W1[o] = h1;
}

// ---------------- kernel 4: score = S*W, 256x256 tile, counted-vmcnt dbuf, fused argmin ----------------
__global__ __launch_bounds__(256, 1) void score_k(const ushort* __restrict__ S0, const ushort* __restrict__ S1,
                                                  const ushort* __restrict__ W0, const ushort* __restrict__ W1,
                                                  float* __restrict__ pval, int* __restrict__ pidx){
  extern __shared__ ushort lds[];                // 2 bufs x 4 panels x 8192 ushorts = 128 KiB
  int tid = threadIdx.x;
  int lane = tid & 63, wid = tid >> 6;
  int wm = wid >> 1, wn = wid & 1;               // 2x2 waves -> 128x128 per wave
  int g = lane >> 4, lr = lane & 15;
  int gsw = g ^ ((lr >> 1) & 3);                 // swizzled granule (lane-constant)

  // XCD-aware decode: 256 blocks, 32 per XCD; 4 col-panels x 8 row-panels per XCD
  int id = blockIdx.x;
  int xcd = id & 7, slot = id >> 3;
  int cidx = slot & 3, ridx = (xcd << 3) | (slot >> 2);
  int n0 = ridx * 256, c0 = cidx * 256;

  // per-wave staging source (one split-panel per wave)
  const ushort* src0;
  size_t kstride;
  if      (wid == 0){ src0 = S0 + (size_t)n0*32; kstride = (size_t)NP*32; }
  else if (wid == 1){ src0 = S1 + (size_t)n0*32; kstride = (size_t)NP*32; }
  else if (wid == 2){ src0 = W0 + (size_t)c0*32; kstride = (size_t)CBS*32; }
  else              { src0 = W1 + (size_t)c0*32; kstride = (size_t)CBS*32; }

  f32x4 acc[8][8] = {};

  // prologue: stage kb=0 into buf 0
  {
    ushort* dst = lds + (size_t)wid*8192;
#pragma unroll
    for (int q = 0; q < 16; ++q) GLL16(src0 + q*512 + lane*8, dst + q*512);
  }
  int buf = 0;
  for (int kb = 0; kb < KB; ++kb){
    if (kb + 1 < KB){                            // issue next-tile loads, keep in flight
      const ushort* s = src0 + (size_t)(kb+1)*kstride;
      ushort* dst = lds + (size_t)((buf^1)*4 + wid)*8192;
#pragma unroll
      for (int q = 0; q < 16; ++q) GLL16(s + q*512 + lane*8, dst + q*512);
      asm volatile("s_waitcnt vmcnt(16)" ::: "memory");   // wait current tile only
    } else {
      asm volatile("s_waitcnt vmcnt(0)" ::: "memory");
    }
    __builtin_amdgcn_s_barrier();
    __builtin_amdgcn_sched_barrier(0);

    const ushort* A0 = lds + (size_t)(buf*4 + 0)*8192;
    const ushort* A1 = lds + (size_t)(buf*4 + 1)*8192;
    const ushort* B0 = lds + (size_t)(buf*4 + 2)*8192;
    const ushort* B1 = lds + (size_t)(buf*4 + 3)*8192;

    bfrag a0[8], a1[8], b0[8], b1[8];
#pragma unroll
    for (int mt = 0; mt < 8; ++mt){
      int off = (wm*128 + mt*16 + lr)*32 + gsw*8;
      a0[mt] = *(const bfrag*)&A0[off];
      a1[mt] = *(const bfrag*)&A1[off];
    }
#pragma unroll
    for (int nt = 0; nt < 8; ++nt){
      int off = (wn*128 + nt*16 + lr)*32 + gsw*8;
      b0[nt] = *(const bfrag*)&B0[off];
      b1[nt] = *(const bfrag*)&B1[off];
    }
#pragma unroll
    for (int mt = 0; mt < 8; ++mt)
#pragma unroll
      for (int nt = 0; nt < 8; ++nt){
        acc[mt][nt] = __builtin_amdgcn_mfma_f32_16x16x32_bf16(a0[mt], b0[nt], acc[mt][nt], 0,0,0);
        acc[mt][nt] = __builtin_amdgcn_mfma_f32_16x16x32_bf16(a0[mt], b1[nt], acc[mt][nt], 0,0,0);
        acc[mt][nt] = __builtin_amdgcn_mfma_f32_16x16x32_bf16(a1[mt], b0[nt], acc[mt][nt], 0,0,0);
      }
    __builtin_amdgcn_sched_barrier(0);
    __builtin_amdgcn_s_barrier();
    buf ^= 1;
  }

  // epilogue: dist = -2*acc (norms folded); per-row argmin, first-index tie-break
#pragma unroll
  for (int mt = 0; mt < 8; ++mt){
    float bv[4]; int bi[4];
#pragma unroll
    for (int r = 0; r < 4; ++r){
      float best = 3.4e38f; int besti = 0;
#pragma unroll
      for (int nt = 0; nt < 8; ++nt){            // nt ascending == col ascending
        float d = -2.f * acc[mt][nt][r];
        int c = c0 + wn*128 + nt*16 + lr;
        if (d < best){ best = d; besti = c; }
      }
      bv[r] = best; bi[r] = besti;
    }
#pragma unroll
    for (int off = 1; off < 16; off <<= 1){
#pragma unroll
      for (int r = 0; r < 4; ++r){
        float ov = __shfl_xor(bv[r], off);
        int   oi = __shfl_xor(bi[r], off);
        if (ov < bv[r] || (ov == bv[r] && oi < bi[r])){ bv[r] = ov; bi[r] = oi; }
      }
    }
    if (lr == 0){
      int p = cidx*2 + wn;
#pragma unroll
      for (int r = 0; r < 4; ++r){
        int n = n0 + wm*128 + mt*16 + g*4 + r;
        pval[(size_t)p*NP + n] = bv[r];
        pidx[(size_t)p*NP + n] = bi[r];
      }
    }
  }
}

// ---------------- kernel 5: combine 8 partial argmins -> labels ----------------
__global__ void combine_k(const float* __restrict__ pval, const int* __restrict__ pidx,
                          const int* __restrict__ len, float* __restrict__ lb){
  int n = blockIdx.x * 256 + threadIdx.x;
  if (n >= NROW) return;
  float bv = pval[n]; int bi = pidx[n];
#pragma unroll
  for (int p = 1; p < 8; ++p){
    float v = pval[(size_t)p*NP + n]; int ii = pidx[(size_t)p*NP + n];
    if (v < bv || (v == bv && ii < bi)){ bv = v; bi = ii; }
  }
  int b = n / T2_, t2 = n - b * T2_;
  lb[n] = (t2 < label_len(len[b])) ? (float)(bi + 1) : 0.f;
}

// ---------------- kernel 6: mask (threefry uniform, bit-exact) ----------------
__device__ inline void emit_mask(const int* len, float* md, int i, uint32_t bits){
  float u = __uint_as_float((bits >> 9) | 0x3F800000u) - 1.0f;
  int b = i / T2_, t2 = i - b * T2_;
  bool m = (u < 0.1f) && (t2 < label_len(len[b]));
  md[i] = m ? 1.0f : 0.0f;
}

__global__ void mask_k(const int* __restrict__ len, float* __restrict__ md, uint32_t km0, uint32_t km1){
  int j = blockIdx.x * 256 + threadIdx.x;
  if (j >= HMASK) return;
  uint32_t x0 = (uint32_t)j, x1 = (uint32_t)(j + HMASK);
  tf2x32(km0, km1, x0, x1);
  emit_mask(len, md, j, x0);
  emit_mask(len, md, j + HMASK, x1);
}

// ---------------- kernel 7: masked_feats (threefry normal, bit-exact bits) ----------------
__device__ inline void emit_feat(const float* aug, const float* md, float* mf, int i, uint32_t bits){
  int tabs = i / D_;
  int t = tabs & (T_ - 1);
  int b = i / (D_ * T_);
  int lo = (t < 3) ? 0 : ((t - 3) >> 2);
  int hi = t >> 2; if (hi > T2_ - 1) hi = T2_ - 1;
  bool m = false;
  for (int t2 = lo; t2 <= hi; ++t2) m = m || (md[b * T2_ + t2] != 0.f);
  float v;
  if (m){
    float f = __uint_as_float((bits >> 9) | 0x3F800000u) - 1.0f;
    const float LOV = -0.99999994f;
    float u = fmaf(f, 2.0f, LOV);
    u = fmaxf(LOV, u);
    v = 0.1f * (1.41421356f * erfinv_f(u));
  } else {
    v = aug[i];
  }
  mf[i] = v;
}

__global__ void feats_k(const float* __restrict__ aug, const float* __restrict__ md,
                        float* __restrict__ mf, uint32_t kn0, uint32_t kn1){
  int j = blockIdx.x * 256 + threadIdx.x;
  uint32_t x0 = (uint32_t)j, x1 = (uint32_t)(j + HN);
  tf2x32(kn0, kn1, x0, x1);
  emit_feat(aug, md, mf, j, x0);
  emit_feat(aug, md, mf, j + HN, x1);
}

// ---------------- host ----------------
extern "C" void kernel_launch(void* const* d_in, const int* in_sizes, int n_in,
                              void* d_out, int out_size, void* d_ws, size_t ws_size,
                              hipStream_t stream){
  const float* raw  = (const float*)d_in[0];
  const float* aug  = (const float*)d_in[1];
  const int*   len  = (const int*)  d_in[2];
  const float* proj = (const float*)d_in[3];
  const float* cb   = (const float*)d_in[4];

  float* out = (float*)d_out;
  float* mf  = out;                       // (B,T,D)   5,242,880
  float* lb  = out + 5242880;             // (1,B,T2)     16,352
  float* md  = out + 5259232;             // (B,T2)       16,352

  ushort* w  = (ushort*)d_ws;
  ushort* W0 = w;                                   // KB*CBS*32 = 753,664 ushorts
  ushort* W1 = W0 + (size_t)KB*CBS*32;
  ushort* S0 = W1 + (size_t)KB*CBS*32;              // KB*NP*32 = 12,058,624 ushorts
  ushort* S1 = S0 + (size_t)KB*NP*32;
  float* pval = (float*)(S1 + (size_t)KB*NP*32);    // 16*NP floats (8 used)
  int*   pidx = (int*)(pval + (size_t)16*NP);       // 16*NP ints
  float* Wp   = (float*)(pidx + (size_t)16*NP);     // 4*GK*CBS floats = 11.8MB

  // raise dynamic LDS cap for the 128 KiB double-buffer (idempotent, not a stream op)
  hipFuncSetAttribute((const void*)score_k, hipFuncAttributeMaxDynamicSharedMemorySize, 131072);

  // JAX: key(42) -> split -> (km, kn)
  uint32_t a0 = 0u, a1 = 2u, b0 = 1u, b1 = 3u;
  tf2x32(0u, 42u, a0, a1);
  tf2x32(0u, 42u, b0, b1);
  uint32_t km0 = a0, km1 = b0, kn0 = a1, kn1 = b1;

  cbnorm_k<<<CBS, 64, 0, stream>>>(cb, W0, W1);
  wgemm_k<<<dim3(CBS / 64, 12, 4), 256, 0, stream>>>(proj, cb, Wp);
  wreduce_k<<<(GK * CBS) / 256, 256, 0, stream>>>(Wp, W0, W1);
  gather_k<<<(KB * NP * 4) / 256, 256, 0, stream>>>(raw, S0, S1);
  score_k<<<256, 256, 131072, stream>>>(S0, S1, W0, W1, pval, pidx);
  combine_k<<<(NROW + 255) / 256, 256, 0, stream>>>(pval, pidx, len, lb);
  mask_k<<<(HMASK + 255) / 256, 256, 0, stream>>>(len, md, km0, km1);
  feats_k<<<HN / 256, 256, 0, stream>>>(aug, md, mf, kn0, kn1);
}